// Round 1
// baseline (1940.660 us; speedup 1.0000x reference)
//
#include <hip/hip_runtime.h>
#include <math.h>

#define NLEV 16
#define TSIZE 524288
#define TMASK (TSIZE - 1)
#define P1 2654435761u
#define P2 805459861u

struct ResParams { int res[NLEV]; int dense[NLEV]; };

__global__ __launch_bounds__(256) void hashgrid_mlp_kernel(
    const float* __restrict__ xyzs,
    const float* __restrict__ tables,
    const float* __restrict__ W1,
    const float* __restrict__ W2,
    float* __restrict__ out_sigma,
    float* __restrict__ out_geo,
    ResParams rp)
{
    __shared__ float sW1t[64 * 32];   // W1 transposed: sW1t[j][k]
    __shared__ float sW2[64 * 16];    // W2 row-major:  sW2[j][q]
    __shared__ float sGeo[256 * 15];  // per-wave transpose staging

    const int tid = threadIdx.x;

    // Stage weights (W1 transposed so each j-row is contiguous for float4 reads)
    for (int i = tid; i < 2048; i += 256) {
        int k = i >> 6, j = i & 63;
        sW1t[j * 32 + k] = W1[i];
    }
    for (int i = tid; i < 1024; i += 256) sW2[i] = W2[i];
    __syncthreads();

    const int gid = blockIdx.x * 256 + tid;
    const float x = xyzs[3 * gid + 0];
    const float y = xyzs[3 * gid + 1];
    const float z = xyzs[3 * gid + 2];
    const float x0 = fminf(fmaxf((x + 1.0f) * 0.5f, 0.0f), 1.0f);
    const float y0 = fminf(fmaxf((y + 1.0f) * 0.5f, 0.0f), 1.0f);
    const float z0 = fminf(fmaxf((z + 1.0f) * 0.5f, 0.0f), 1.0f);

    float enc[32];
    const float2* tb = (const float2*)tables;

#pragma unroll
    for (int l = 0; l < NLEV; ++l) {
        const int res = rp.res[l];
        const float rf = (float)res;
        const float px = x0 * rf, py = y0 * rf, pz = z0 * rf;
        const float fx = floorf(px), fy = floorf(py), fz = floorf(pz);
        const float rx = px - fx, ry = py - fy, rz = pz - fz;
        const unsigned ix = (unsigned)fx, iy = (unsigned)fy, iz = (unsigned)fz;

        unsigned idx[8];
        if (rp.dense[l]) {
            // corner offsets: (c>>2, (c>>1)&1, c&1) applied to (x,y,z);
            // idx = x + s*(y + s*z)
            const unsigned s = (unsigned)(res + 1);
            const unsigned ss = s * s;
            const unsigned base = ix + s * (iy + s * iz);
            idx[0] = base;               // (0,0,0)
            idx[1] = base + ss;          // (0,0,1)
            idx[2] = base + s;           // (0,1,0)
            idx[3] = base + s + ss;      // (0,1,1)
            idx[4] = base + 1u;          // (1,0,0)
            idx[5] = base + 1u + ss;     // (1,0,1)
            idx[6] = base + 1u + s;      // (1,1,0)
            idx[7] = base + 1u + s + ss; // (1,1,1)
        } else {
            const unsigned ax0 = ix,            ax1 = ix + 1u;
            const unsigned by0 = iy * P1,       by1 = (iy + 1u) * P1;
            const unsigned cz0 = iz * P2,       cz1 = (iz + 1u) * P2;
            idx[0] = (ax0 ^ by0 ^ cz0) & TMASK;
            idx[1] = (ax0 ^ by0 ^ cz1) & TMASK;
            idx[2] = (ax0 ^ by1 ^ cz0) & TMASK;
            idx[3] = (ax0 ^ by1 ^ cz1) & TMASK;
            idx[4] = (ax1 ^ by0 ^ cz0) & TMASK;
            idx[5] = (ax1 ^ by0 ^ cz1) & TMASK;
            idx[6] = (ax1 ^ by1 ^ cz0) & TMASK;
            idx[7] = (ax1 ^ by1 ^ cz1) & TMASK;
        }

        const float2* tl = tb + (size_t)l * TSIZE;
        float2 v[8];
#pragma unroll
        for (int c = 0; c < 8; ++c) v[c] = tl[idx[c]];

        const float wx0 = 1.0f - rx, wx1 = rx;
        const float wy0 = 1.0f - ry, wy1 = ry;
        const float wz0 = 1.0f - rz, wz1 = rz;
        float e0 = 0.0f, e1 = 0.0f;
#pragma unroll
        for (int c = 0; c < 8; ++c) {
            const float wx = (c & 4) ? wx1 : wx0;
            const float wy = (c & 2) ? wy1 : wy0;
            const float wz = (c & 1) ? wz1 : wz0;
            const float w = (wx * wy) * wz;
            e0 += w * v[c].x;
            e1 += w * v[c].y;
        }
        enc[2 * l]     = e0;
        enc[2 * l + 1] = e1;
    }

    // MLP: out[q] = sum_j relu(sum_k enc[k]*W1[k][j]) * W2[j][q]
    float outv[16];
#pragma unroll
    for (int q = 0; q < 16; ++q) outv[q] = 0.0f;

    for (int j = 0; j < 64; ++j) {
        const float4* wrow = (const float4*)&sW1t[j * 32];
        float hj = 0.0f;
#pragma unroll
        for (int kk = 0; kk < 8; ++kk) {
            const float4 wv = wrow[kk];
            hj += enc[4 * kk + 0] * wv.x;
            hj += enc[4 * kk + 1] * wv.y;
            hj += enc[4 * kk + 2] * wv.z;
            hj += enc[4 * kk + 3] * wv.w;
        }
        hj = fmaxf(hj, 0.0f);
        const float4* w2row = (const float4*)&sW2[j * 16];
#pragma unroll
        for (int qq = 0; qq < 4; ++qq) {
            const float4 w2v = w2row[qq];
            outv[4 * qq + 0] += hj * w2v.x;
            outv[4 * qq + 1] += hj * w2v.y;
            outv[4 * qq + 2] += hj * w2v.z;
            outv[4 * qq + 3] += hj * w2v.w;
        }
    }

    out_sigma[gid] = expf(outv[0]);

    // Coalesce geo writes via per-wave LDS transpose
    const int wave = tid >> 6;
    const int lane = tid & 63;
    float* gs = &sGeo[wave * 960];
#pragma unroll
    for (int q = 1; q < 16; ++q) gs[lane * 15 + (q - 1)] = outv[q];
    __syncthreads();
    const size_t wbase = (size_t)(blockIdx.x * 256 + wave * 64) * 15;
#pragma unroll
    for (int j = 0; j < 15; ++j)
        out_geo[wbase + (size_t)(j * 64 + lane)] = gs[j * 64 + lane];
}

extern "C" void kernel_launch(void* const* d_in, const int* in_sizes, int n_in,
                              void* d_out, int out_size, void* d_ws, size_t ws_size,
                              hipStream_t stream) {
    const float* xyzs   = (const float*)d_in[0];
    const float* tables = (const float*)d_in[1];
    const float* W1     = (const float*)d_in[2];
    const float* W2     = (const float*)d_in[3];
    float* out = (float*)d_out;

    const int N = in_sizes[0] / 3;

    // Replicate reference RES computation bit-for-bit in float64 (same libm
    // as the Python harness): PLS = exp(log(2048/16)/15); res = ceil(16*PLS^l).
    // l=15 sits ~1e-11 from integer 2048 -> must not hard-code.
    ResParams rp;
    const double PLS = exp(log(2048.0 / 16.0) / 15.0);
    for (int l = 0; l < NLEV; ++l) {
        const double r = ceil(16.0 * pow(PLS, (double)l));
        rp.res[l] = (int)r;
        const long long s = (long long)r + 1;
        rp.dense[l] = (s * s * s <= (long long)TSIZE) ? 1 : 0;
    }

    float* out_sigma = out;
    float* out_geo   = out + N;

    hipLaunchKernelGGL(hashgrid_mlp_kernel,
                       dim3(N / 256), dim3(256), 0, stream,
                       xyzs, tables, W1, W2, out_sigma, out_geo, rp);
}

// Round 2
// 1438.876 us; speedup vs baseline: 1.3487x; 1.3487x over previous
//
#include <hip/hip_runtime.h>
#include <math.h>

#define NLEV 16
#define TSIZE 524288
#define TMASK (TSIZE - 1)
#define P1 2654435761u
#define P2 805459861u

struct ResParams { int res[NLEV]; int dense[NLEV]; };

__device__ __forceinline__ float clamp01f(float v) {
    return fminf(fmaxf(v, 0.0f), 1.0f);
}

__device__ __forceinline__ void corner_idx(unsigned ix, unsigned iy, unsigned iz,
                                           int res, int dense, unsigned idx[8]) {
    if (dense) {
        // corner offsets (c>>2, (c>>1)&1, c&1) on (x,y,z); idx = x + s*(y + s*z)
        const unsigned s = (unsigned)(res + 1);
        const unsigned ss = s * s;
        const unsigned base = ix + s * (iy + s * iz);
        idx[0] = base;
        idx[1] = base + ss;
        idx[2] = base + s;
        idx[3] = base + s + ss;
        idx[4] = base + 1u;
        idx[5] = base + 1u + ss;
        idx[6] = base + 1u + s;
        idx[7] = base + 1u + s + ss;
    } else {
        const unsigned ax0 = ix,          ax1 = ix + 1u;
        const unsigned by0 = iy * P1,     by1 = (iy + 1u) * P1;
        const unsigned cz0 = iz * P2,     cz1 = (iz + 1u) * P2;
        idx[0] = (ax0 ^ by0 ^ cz0) & TMASK;
        idx[1] = (ax0 ^ by0 ^ cz1) & TMASK;
        idx[2] = (ax0 ^ by1 ^ cz0) & TMASK;
        idx[3] = (ax0 ^ by1 ^ cz1) & TMASK;
        idx[4] = (ax1 ^ by0 ^ cz0) & TMASK;
        idx[5] = (ax1 ^ by0 ^ cz1) & TMASK;
        idx[6] = (ax1 ^ by1 ^ cz0) & TMASK;
        idx[7] = (ax1 ^ by1 ^ cz1) & TMASK;
    }
}

// ---------------- per-level-range encoding kernel (L2-resident tables) -----
template<int L0, int L1>
__global__ __launch_bounds__(256) void enc_range_kernel(
    const float* __restrict__ xyzs,
    const float* __restrict__ tables,
    float2* __restrict__ enc_ws,     // [NLEV][N]
    ResParams rp, int N)
{
    const int gid = blockIdx.x * 256 + threadIdx.x;
    const float x0 = clamp01f((xyzs[3 * gid + 0] + 1.0f) * 0.5f);
    const float y0 = clamp01f((xyzs[3 * gid + 1] + 1.0f) * 0.5f);
    const float z0 = clamp01f((xyzs[3 * gid + 2] + 1.0f) * 0.5f);
    const float2* tb = (const float2*)tables;

#pragma unroll
    for (int l = L0; l < L1; ++l) {
        const int res = rp.res[l];
        const float rf = (float)res;
        const float px = x0 * rf, py = y0 * rf, pz = z0 * rf;
        const float fx = floorf(px), fy = floorf(py), fz = floorf(pz);
        const float rx = px - fx, ry = py - fy, rz = pz - fz;
        const unsigned ix = (unsigned)fx, iy = (unsigned)fy, iz = (unsigned)fz;

        unsigned idx[8];
        corner_idx(ix, iy, iz, res, rp.dense[l], idx);

        const float2* tl = tb + (size_t)l * TSIZE;
        float2 v[8];
#pragma unroll
        for (int c = 0; c < 8; ++c) v[c] = tl[idx[c]];

        const float wx0 = 1.0f - rx, wx1 = rx;
        const float wy0 = 1.0f - ry, wy1 = ry;
        const float wz0 = 1.0f - rz, wz1 = rz;
        float e0 = 0.0f, e1 = 0.0f;
#pragma unroll
        for (int c = 0; c < 8; ++c) {
            const float wx = (c & 4) ? wx1 : wx0;
            const float wy = (c & 2) ? wy1 : wy0;
            const float wz = (c & 1) ? wz1 : wz0;
            const float w = (wx * wy) * wz;
            e0 += w * v[c].x;
            e1 += w * v[c].y;
        }
        enc_ws[(size_t)l * N + gid] = make_float2(e0, e1);
    }
}

// ---------------- MLP kernel ----------------------------------------------
__global__ __launch_bounds__(256) void mlp_kernel(
    const float2* __restrict__ enc_ws,   // [NLEV][N]
    const float* __restrict__ W1,
    const float* __restrict__ W2,
    float* __restrict__ out_sigma,
    float* __restrict__ out_geo,
    int N)
{
    __shared__ float sW1t[64 * 32];   // W1 transposed: sW1t[j][k]
    __shared__ float sW2[64 * 16];    // W2 row-major
    __shared__ float sGeo[256 * 15];  // per-wave transpose staging

    const int tid = threadIdx.x;
    for (int i = tid; i < 2048; i += 256) {
        int k = i >> 6, j = i & 63;
        sW1t[j * 32 + k] = W1[i];
    }
    for (int i = tid; i < 1024; i += 256) sW2[i] = W2[i];
    __syncthreads();

    const int gid = blockIdx.x * 256 + tid;
    float enc[32];
#pragma unroll
    for (int l = 0; l < NLEV; ++l) {
        float2 e = enc_ws[(size_t)l * N + gid];
        enc[2 * l]     = e.x;
        enc[2 * l + 1] = e.y;
    }

    float outv[16];
#pragma unroll
    for (int q = 0; q < 16; ++q) outv[q] = 0.0f;

    for (int j = 0; j < 64; ++j) {
        const float4* wrow = (const float4*)&sW1t[j * 32];
        float hj = 0.0f;
#pragma unroll
        for (int kk = 0; kk < 8; ++kk) {
            const float4 wv = wrow[kk];
            hj += enc[4 * kk + 0] * wv.x;
            hj += enc[4 * kk + 1] * wv.y;
            hj += enc[4 * kk + 2] * wv.z;
            hj += enc[4 * kk + 3] * wv.w;
        }
        hj = fmaxf(hj, 0.0f);
        const float4* w2row = (const float4*)&sW2[j * 16];
#pragma unroll
        for (int qq = 0; qq < 4; ++qq) {
            const float4 w2v = w2row[qq];
            outv[4 * qq + 0] += hj * w2v.x;
            outv[4 * qq + 1] += hj * w2v.y;
            outv[4 * qq + 2] += hj * w2v.z;
            outv[4 * qq + 3] += hj * w2v.w;
        }
    }

    out_sigma[gid] = expf(outv[0]);

    const int wave = tid >> 6;
    const int lane = tid & 63;
    float* gs = &sGeo[wave * 960];
#pragma unroll
    for (int q = 1; q < 16; ++q) gs[lane * 15 + (q - 1)] = outv[q];
    __syncthreads();
    const size_t wbase = (size_t)(blockIdx.x * 256 + wave * 64) * 15;
#pragma unroll
    for (int j = 0; j < 15; ++j)
        out_geo[wbase + (size_t)(j * 64 + lane)] = gs[j * 64 + lane];
}

// ---------------- fallback: proven fused kernel (R1, passed) ---------------
__global__ __launch_bounds__(256) void hashgrid_fused_kernel(
    const float* __restrict__ xyzs,
    const float* __restrict__ tables,
    const float* __restrict__ W1,
    const float* __restrict__ W2,
    float* __restrict__ out_sigma,
    float* __restrict__ out_geo,
    ResParams rp)
{
    __shared__ float sW1t[64 * 32];
    __shared__ float sW2[64 * 16];
    __shared__ float sGeo[256 * 15];

    const int tid = threadIdx.x;
    for (int i = tid; i < 2048; i += 256) {
        int k = i >> 6, j = i & 63;
        sW1t[j * 32 + k] = W1[i];
    }
    for (int i = tid; i < 1024; i += 256) sW2[i] = W2[i];
    __syncthreads();

    const int gid = blockIdx.x * 256 + tid;
    const float x0 = clamp01f((xyzs[3 * gid + 0] + 1.0f) * 0.5f);
    const float y0 = clamp01f((xyzs[3 * gid + 1] + 1.0f) * 0.5f);
    const float z0 = clamp01f((xyzs[3 * gid + 2] + 1.0f) * 0.5f);

    float enc[32];
    const float2* tb = (const float2*)tables;

#pragma unroll
    for (int l = 0; l < NLEV; ++l) {
        const int res = rp.res[l];
        const float rf = (float)res;
        const float px = x0 * rf, py = y0 * rf, pz = z0 * rf;
        const float fx = floorf(px), fy = floorf(py), fz = floorf(pz);
        const float rx = px - fx, ry = py - fy, rz = pz - fz;
        const unsigned ix = (unsigned)fx, iy = (unsigned)fy, iz = (unsigned)fz;

        unsigned idx[8];
        corner_idx(ix, iy, iz, res, rp.dense[l], idx);

        const float2* tl = tb + (size_t)l * TSIZE;
        float2 v[8];
#pragma unroll
        for (int c = 0; c < 8; ++c) v[c] = tl[idx[c]];

        const float wx0 = 1.0f - rx, wx1 = rx;
        const float wy0 = 1.0f - ry, wy1 = ry;
        const float wz0 = 1.0f - rz, wz1 = rz;
        float e0 = 0.0f, e1 = 0.0f;
#pragma unroll
        for (int c = 0; c < 8; ++c) {
            const float wx = (c & 4) ? wx1 : wx0;
            const float wy = (c & 2) ? wy1 : wy0;
            const float wz = (c & 1) ? wz1 : wz0;
            const float w = (wx * wy) * wz;
            e0 += w * v[c].x;
            e1 += w * v[c].y;
        }
        enc[2 * l]     = e0;
        enc[2 * l + 1] = e1;
    }

    float outv[16];
#pragma unroll
    for (int q = 0; q < 16; ++q) outv[q] = 0.0f;

    for (int j = 0; j < 64; ++j) {
        const float4* wrow = (const float4*)&sW1t[j * 32];
        float hj = 0.0f;
#pragma unroll
        for (int kk = 0; kk < 8; ++kk) {
            const float4 wv = wrow[kk];
            hj += enc[4 * kk + 0] * wv.x;
            hj += enc[4 * kk + 1] * wv.y;
            hj += enc[4 * kk + 2] * wv.z;
            hj += enc[4 * kk + 3] * wv.w;
        }
        hj = fmaxf(hj, 0.0f);
        const float4* w2row = (const float4*)&sW2[j * 16];
#pragma unroll
        for (int qq = 0; qq < 4; ++qq) {
            const float4 w2v = w2row[qq];
            outv[4 * qq + 0] += hj * w2v.x;
            outv[4 * qq + 1] += hj * w2v.y;
            outv[4 * qq + 2] += hj * w2v.z;
            outv[4 * qq + 3] += hj * w2v.w;
        }
    }

    out_sigma[gid] = expf(outv[0]);

    const int wave = tid >> 6;
    const int lane = tid & 63;
    float* gs = &sGeo[wave * 960];
#pragma unroll
    for (int q = 1; q < 16; ++q) gs[lane * 15 + (q - 1)] = outv[q];
    __syncthreads();
    const size_t wbase = (size_t)(blockIdx.x * 256 + wave * 64) * 15;
#pragma unroll
    for (int j = 0; j < 15; ++j)
        out_geo[wbase + (size_t)(j * 64 + lane)] = gs[j * 64 + lane];
}

extern "C" void kernel_launch(void* const* d_in, const int* in_sizes, int n_in,
                              void* d_out, int out_size, void* d_ws, size_t ws_size,
                              hipStream_t stream) {
    const float* xyzs   = (const float*)d_in[0];
    const float* tables = (const float*)d_in[1];
    const float* W1     = (const float*)d_in[2];
    const float* W2     = (const float*)d_in[3];
    float* out = (float*)d_out;

    const int N = in_sizes[0] / 3;

    // Replicate reference RES computation bit-for-bit in float64 (same libm
    // as the Python harness): PLS = exp(log(2048/16)/15); res = ceil(16*PLS^l).
    // l=15 sits ~1e-11 from integer 2048 -> must not hard-code.
    ResParams rp;
    const double PLS = exp(log(2048.0 / 16.0) / 15.0);
    for (int l = 0; l < NLEV; ++l) {
        const double r = ceil(16.0 * pow(PLS, (double)l));
        rp.res[l] = (int)r;
        const long long s = (long long)r + 1;
        rp.dense[l] = (s * s * s <= (long long)TSIZE) ? 1 : 0;
    }

    float* out_sigma = out;
    float* out_geo   = out + N;

    const size_t ws_needed = (size_t)NLEV * (size_t)N * 2 * sizeof(float);
    const dim3 grid(N / 256), block(256);

    if (ws_size >= ws_needed) {
        float2* enc_ws = (float2*)d_ws;
        // dense levels 0..4 share one kernel (combined tables ~2.8 MB, L2-fit);
        // each hashed level (4 MB table == one XCD L2) gets its own kernel.
        enc_range_kernel<0, 5><<<grid, block, 0, stream>>>(xyzs, tables, enc_ws, rp, N);
        enc_range_kernel<5, 6><<<grid, block, 0, stream>>>(xyzs, tables, enc_ws, rp, N);
        enc_range_kernel<6, 7><<<grid, block, 0, stream>>>(xyzs, tables, enc_ws, rp, N);
        enc_range_kernel<7, 8><<<grid, block, 0, stream>>>(xyzs, tables, enc_ws, rp, N);
        enc_range_kernel<8, 9><<<grid, block, 0, stream>>>(xyzs, tables, enc_ws, rp, N);
        enc_range_kernel<9, 10><<<grid, block, 0, stream>>>(xyzs, tables, enc_ws, rp, N);
        enc_range_kernel<10, 11><<<grid, block, 0, stream>>>(xyzs, tables, enc_ws, rp, N);
        enc_range_kernel<11, 12><<<grid, block, 0, stream>>>(xyzs, tables, enc_ws, rp, N);
        enc_range_kernel<12, 13><<<grid, block, 0, stream>>>(xyzs, tables, enc_ws, rp, N);
        enc_range_kernel<13, 14><<<grid, block, 0, stream>>>(xyzs, tables, enc_ws, rp, N);
        enc_range_kernel<14, 15><<<grid, block, 0, stream>>>(xyzs, tables, enc_ws, rp, N);
        enc_range_kernel<15, 16><<<grid, block, 0, stream>>>(xyzs, tables, enc_ws, rp, N);
        mlp_kernel<<<grid, block, 0, stream>>>(enc_ws, W1, W2, out_sigma, out_geo, N);
    } else {
        hashgrid_fused_kernel<<<grid, block, 0, stream>>>(
            xyzs, tables, W1, W2, out_sigma, out_geo, rp);
    }
}

// Round 3
// 1429.167 us; speedup vs baseline: 1.3579x; 1.0068x over previous
//
#include <hip/hip_runtime.h>
#include <math.h>

#define NLEV 16
#define TSIZE 524288
#define TMASK (TSIZE - 1)
#define P1 2654435761u
#define P2 805459861u

struct ResParams { int res[NLEV]; int dense[NLEV]; };

__device__ __forceinline__ float clamp01f(float v) {
    return fminf(fmaxf(v, 0.0f), 1.0f);
}

// bf16 helpers (manual, RNE; values are tame: no NaN/Inf/denorm concerns)
__device__ __forceinline__ unsigned f2bf(float f) {
    union { float f; unsigned u; } c; c.f = f;
    return (c.u + 0x7FFFu + ((c.u >> 16) & 1u)) >> 16;
}
__device__ __forceinline__ float bflo(unsigned u) {
    union { unsigned u; float f; } c; c.u = u << 16; return c.f;
}
__device__ __forceinline__ float bfhi(unsigned u) {
    union { unsigned u; float f; } c; c.u = u & 0xFFFF0000u; return c.f;
}

// ---------------- prep: fp32 tables -> packed bf16, W1 -> W1t --------------
__global__ __launch_bounds__(256) void prep_kernel(
    const float* __restrict__ tables,   // [NLEV*TSIZE*2]
    const float* __restrict__ W1,       // [32][64]
    const float* __restrict__ W2,       // [64][16]
    unsigned* __restrict__ tbl_bf,      // [NLEV*TSIZE] packed (lo=f0, hi=f1)
    float* __restrict__ W1t,            // [64][32]
    float* __restrict__ W2c)            // [64][16]
{
    const int t = blockIdx.x * 256 + threadIdx.x;   // one float4 = 2 entries
    const float4 v = *(const float4*)(tables + (size_t)t * 4);
    uint2 o;
    o.x = f2bf(v.x) | (f2bf(v.y) << 16);
    o.y = f2bf(v.z) | (f2bf(v.w) << 16);
    *(uint2*)(tbl_bf + (size_t)t * 2) = o;

    if (blockIdx.x == 0) {
        for (int i = threadIdx.x; i < 2048; i += 256)
            W1t[(i & 63) * 32 + (i >> 6)] = W1[i];
        for (int i = threadIdx.x; i < 1024; i += 256)
            W2c[i] = W2[i];
    }
}

// ---------------- dense levels 0..4 (exact fp32 tables) --------------------
__global__ __launch_bounds__(256) void enc_dense_kernel(
    const float* __restrict__ xyzs,
    const float* __restrict__ tables,   // original fp32
    unsigned* __restrict__ enc_ws,      // [NLEV][N] packed bf16 pairs
    ResParams rp, int N)
{
    const int gid = blockIdx.x * 256 + threadIdx.x;
    const float x0 = clamp01f((__builtin_nontemporal_load(xyzs + 3 * gid + 0) + 1.0f) * 0.5f);
    const float y0 = clamp01f((__builtin_nontemporal_load(xyzs + 3 * gid + 1) + 1.0f) * 0.5f);
    const float z0 = clamp01f((__builtin_nontemporal_load(xyzs + 3 * gid + 2) + 1.0f) * 0.5f);
    const float2* tb = (const float2*)tables;

#pragma unroll
    for (int l = 0; l < 5; ++l) {
        const int res = rp.res[l];
        const float rf = (float)res;
        const float px = x0 * rf, py = y0 * rf, pz = z0 * rf;
        const float fx = floorf(px), fy = floorf(py), fz = floorf(pz);
        const float rx = px - fx, ry = py - fy, rz = pz - fz;
        const unsigned ix = (unsigned)fx, iy = (unsigned)fy, iz = (unsigned)fz;

        const unsigned s = (unsigned)(res + 1);
        const unsigned ss = s * s;
        const unsigned base = ix + s * (iy + s * iz);
        unsigned idx[8];
        idx[0] = base;               // (0,0,0)
        idx[1] = base + ss;          // (0,0,1)
        idx[2] = base + s;           // (0,1,0)
        idx[3] = base + s + ss;      // (0,1,1)
        idx[4] = base + 1u;          // (1,0,0)
        idx[5] = base + 1u + ss;     // (1,0,1)
        idx[6] = base + 1u + s;      // (1,1,0)
        idx[7] = base + 1u + s + ss; // (1,1,1)

        const float2* tl = tb + (size_t)l * TSIZE;
        float2 v[8];
#pragma unroll
        for (int c = 0; c < 8; ++c) v[c] = tl[idx[c]];

        const float wx0 = 1.0f - rx, wy0 = 1.0f - ry, wz0 = 1.0f - rz;
        float e0 = 0.0f, e1 = 0.0f;
#pragma unroll
        for (int c = 0; c < 8; ++c) {
            const float wx = (c & 4) ? rx : wx0;
            const float wy = (c & 2) ? ry : wy0;
            const float wz = (c & 1) ? rz : wz0;
            const float w = (wx * wy) * wz;
            e0 += w * v[c].x;
            e1 += w * v[c].y;
        }
        __builtin_nontemporal_store(f2bf(e0) | (f2bf(e1) << 16),
                                    enc_ws + (size_t)l * N + gid);
    }
}

// ---------------- one hashed level (bf16 table, L2-resident) ---------------
__global__ __launch_bounds__(256) void enc_hash_kernel(
    const float* __restrict__ xyzs,
    const unsigned* __restrict__ tbl_bf,
    unsigned* __restrict__ enc_ws,
    int level, int res, int N)
{
    const int gid = blockIdx.x * 256 + threadIdx.x;
    const float x0 = clamp01f((__builtin_nontemporal_load(xyzs + 3 * gid + 0) + 1.0f) * 0.5f);
    const float y0 = clamp01f((__builtin_nontemporal_load(xyzs + 3 * gid + 1) + 1.0f) * 0.5f);
    const float z0 = clamp01f((__builtin_nontemporal_load(xyzs + 3 * gid + 2) + 1.0f) * 0.5f);

    const float rf = (float)res;
    const float px = x0 * rf, py = y0 * rf, pz = z0 * rf;
    const float fx = floorf(px), fy = floorf(py), fz = floorf(pz);
    const float rx = px - fx, ry = py - fy, rz = pz - fz;
    const unsigned ix = (unsigned)fx, iy = (unsigned)fy, iz = (unsigned)fz;

    const unsigned ax0 = ix,        ax1 = ix + 1u;
    const unsigned by0 = iy * P1,   by1 = (iy + 1u) * P1;
    const unsigned cz0 = iz * P2,   cz1 = (iz + 1u) * P2;
    unsigned idx[8];
    idx[0] = (ax0 ^ by0 ^ cz0) & TMASK;
    idx[1] = (ax0 ^ by0 ^ cz1) & TMASK;
    idx[2] = (ax0 ^ by1 ^ cz0) & TMASK;
    idx[3] = (ax0 ^ by1 ^ cz1) & TMASK;
    idx[4] = (ax1 ^ by0 ^ cz0) & TMASK;
    idx[5] = (ax1 ^ by0 ^ cz1) & TMASK;
    idx[6] = (ax1 ^ by1 ^ cz0) & TMASK;
    idx[7] = (ax1 ^ by1 ^ cz1) & TMASK;

    const unsigned* tl = tbl_bf + (size_t)level * TSIZE;
    unsigned v[8];
#pragma unroll
    for (int c = 0; c < 8; ++c) v[c] = tl[idx[c]];

    const float wx0 = 1.0f - rx, wy0 = 1.0f - ry, wz0 = 1.0f - rz;
    float e0 = 0.0f, e1 = 0.0f;
#pragma unroll
    for (int c = 0; c < 8; ++c) {
        const float wx = (c & 4) ? rx : wx0;
        const float wy = (c & 2) ? ry : wy0;
        const float wz = (c & 1) ? rz : wz0;
        const float w = (wx * wy) * wz;
        e0 += w * bflo(v[c]);
        e1 += w * bfhi(v[c]);
    }
    __builtin_nontemporal_store(f2bf(e0) | (f2bf(e1) << 16),
                                enc_ws + (size_t)level * N + gid);
}

// ---------------- MLP: 2 points/thread, uniform weight loads ---------------
__global__ __launch_bounds__(256) void mlp_kernel(
    const unsigned* __restrict__ enc_ws,   // [NLEV][N] packed bf16
    const float* __restrict__ W1t,         // [64][32]
    const float* __restrict__ W2c,         // [64][16]
    float* __restrict__ out_sigma,
    float* __restrict__ out_geo,
    int N)
{
    __shared__ float sGeo[4 * 128 * 15];   // 30 KB, per-wave transpose staging

    const int tid  = threadIdx.x;
    const int wave = tid >> 6;
    const int lane = tid & 63;
    const int base = blockIdx.x * 512 + wave * 128;   // wave owns 128 points
    const int pt0 = base + lane;
    const int pt1 = base + 64 + lane;

    float ea[32], eb[32];
#pragma unroll
    for (int l = 0; l < NLEV; ++l) {
        const unsigned u0 = __builtin_nontemporal_load(enc_ws + (size_t)l * N + pt0);
        const unsigned u1 = __builtin_nontemporal_load(enc_ws + (size_t)l * N + pt1);
        ea[2 * l] = bflo(u0); ea[2 * l + 1] = bfhi(u0);
        eb[2 * l] = bflo(u1); eb[2 * l + 1] = bfhi(u1);
    }

    float oa[16], ob[16];
#pragma unroll
    for (int q = 0; q < 16; ++q) { oa[q] = 0.0f; ob[q] = 0.0f; }

#pragma unroll 4
    for (int j = 0; j < 64; ++j) {
        const float4* wr = (const float4*)(W1t + j * 32);   // uniform -> s_load
        float h0 = 0.0f, h1 = 0.0f;
#pragma unroll
        for (int k = 0; k < 8; ++k) {
            const float4 w = wr[k];
            h0 += ea[4 * k + 0] * w.x; h1 += eb[4 * k + 0] * w.x;
            h0 += ea[4 * k + 1] * w.y; h1 += eb[4 * k + 1] * w.y;
            h0 += ea[4 * k + 2] * w.z; h1 += eb[4 * k + 2] * w.z;
            h0 += ea[4 * k + 3] * w.w; h1 += eb[4 * k + 3] * w.w;
        }
        h0 = fmaxf(h0, 0.0f); h1 = fmaxf(h1, 0.0f);
        const float4* w2 = (const float4*)(W2c + j * 16);
#pragma unroll
        for (int q = 0; q < 4; ++q) {
            const float4 w = w2[q];
            oa[4 * q + 0] += h0 * w.x; ob[4 * q + 0] += h1 * w.x;
            oa[4 * q + 1] += h0 * w.y; ob[4 * q + 1] += h1 * w.y;
            oa[4 * q + 2] += h0 * w.z; ob[4 * q + 2] += h1 * w.z;
            oa[4 * q + 3] += h0 * w.w; ob[4 * q + 3] += h1 * w.w;
        }
    }

    out_sigma[pt0] = expf(oa[0]);
    out_sigma[pt1] = expf(ob[0]);

    float* gs = &sGeo[wave * 1920];
#pragma unroll
    for (int q = 1; q < 16; ++q) gs[lane * 15 + (q - 1)] = oa[q];
#pragma unroll
    for (int q = 1; q < 16; ++q) gs[(64 + lane) * 15 + (q - 1)] = ob[q];
    __syncthreads();
    const size_t wbase = (size_t)base * 15;
#pragma unroll
    for (int j = 0; j < 30; ++j)
        out_geo[wbase + (size_t)(j * 64 + lane)] = gs[j * 64 + lane];
}

// ---------------- fallback: proven fused kernel (R1, passed) ---------------
__global__ __launch_bounds__(256) void hashgrid_fused_kernel(
    const float* __restrict__ xyzs,
    const float* __restrict__ tables,
    const float* __restrict__ W1,
    const float* __restrict__ W2,
    float* __restrict__ out_sigma,
    float* __restrict__ out_geo,
    ResParams rp)
{
    __shared__ float sW1t[64 * 32];
    __shared__ float sW2[64 * 16];
    __shared__ float sGeo[256 * 15];

    const int tid = threadIdx.x;
    for (int i = tid; i < 2048; i += 256) {
        int k = i >> 6, j = i & 63;
        sW1t[j * 32 + k] = W1[i];
    }
    for (int i = tid; i < 1024; i += 256) sW2[i] = W2[i];
    __syncthreads();

    const int gid = blockIdx.x * 256 + tid;
    const float x0 = clamp01f((xyzs[3 * gid + 0] + 1.0f) * 0.5f);
    const float y0 = clamp01f((xyzs[3 * gid + 1] + 1.0f) * 0.5f);
    const float z0 = clamp01f((xyzs[3 * gid + 2] + 1.0f) * 0.5f);

    float enc[32];
    const float2* tb = (const float2*)tables;

#pragma unroll
    for (int l = 0; l < NLEV; ++l) {
        const int res = rp.res[l];
        const float rf = (float)res;
        const float px = x0 * rf, py = y0 * rf, pz = z0 * rf;
        const float fx = floorf(px), fy = floorf(py), fz = floorf(pz);
        const float rx = px - fx, ry = py - fy, rz = pz - fz;
        const unsigned ix = (unsigned)fx, iy = (unsigned)fy, iz = (unsigned)fz;

        unsigned idx[8];
        if (rp.dense[l]) {
            const unsigned s = (unsigned)(res + 1);
            const unsigned ss = s * s;
            const unsigned base = ix + s * (iy + s * iz);
            idx[0] = base;          idx[1] = base + ss;
            idx[2] = base + s;      idx[3] = base + s + ss;
            idx[4] = base + 1u;     idx[5] = base + 1u + ss;
            idx[6] = base + 1u + s; idx[7] = base + 1u + s + ss;
        } else {
            const unsigned ax0 = ix,        ax1 = ix + 1u;
            const unsigned by0 = iy * P1,   by1 = (iy + 1u) * P1;
            const unsigned cz0 = iz * P2,   cz1 = (iz + 1u) * P2;
            idx[0] = (ax0 ^ by0 ^ cz0) & TMASK;
            idx[1] = (ax0 ^ by0 ^ cz1) & TMASK;
            idx[2] = (ax0 ^ by1 ^ cz0) & TMASK;
            idx[3] = (ax0 ^ by1 ^ cz1) & TMASK;
            idx[4] = (ax1 ^ by0 ^ cz0) & TMASK;
            idx[5] = (ax1 ^ by0 ^ cz1) & TMASK;
            idx[6] = (ax1 ^ by1 ^ cz0) & TMASK;
            idx[7] = (ax1 ^ by1 ^ cz1) & TMASK;
        }

        const float2* tl = tb + (size_t)l * TSIZE;
        float2 v[8];
#pragma unroll
        for (int c = 0; c < 8; ++c) v[c] = tl[idx[c]];

        const float wx0 = 1.0f - rx, wy0 = 1.0f - ry, wz0 = 1.0f - rz;
        float e0 = 0.0f, e1 = 0.0f;
#pragma unroll
        for (int c = 0; c < 8; ++c) {
            const float wx = (c & 4) ? rx : wx0;
            const float wy = (c & 2) ? ry : wy0;
            const float wz = (c & 1) ? rz : wz0;
            const float w = (wx * wy) * wz;
            e0 += w * v[c].x;
            e1 += w * v[c].y;
        }
        enc[2 * l]     = e0;
        enc[2 * l + 1] = e1;
    }

    float outv[16];
#pragma unroll
    for (int q = 0; q < 16; ++q) outv[q] = 0.0f;

    for (int j = 0; j < 64; ++j) {
        const float4* wrow = (const float4*)&sW1t[j * 32];
        float hj = 0.0f;
#pragma unroll
        for (int kk = 0; kk < 8; ++kk) {
            const float4 wv = wrow[kk];
            hj += enc[4 * kk + 0] * wv.x;
            hj += enc[4 * kk + 1] * wv.y;
            hj += enc[4 * kk + 2] * wv.z;
            hj += enc[4 * kk + 3] * wv.w;
        }
        hj = fmaxf(hj, 0.0f);
        const float4* w2row = (const float4*)&sW2[j * 16];
#pragma unroll
        for (int qq = 0; qq < 4; ++qq) {
            const float4 w2v = w2row[qq];
            outv[4 * qq + 0] += hj * w2v.x;
            outv[4 * qq + 1] += hj * w2v.y;
            outv[4 * qq + 2] += hj * w2v.z;
            outv[4 * qq + 3] += hj * w2v.w;
        }
    }

    out_sigma[gid] = expf(outv[0]);

    const int wave = tid >> 6;
    const int lane = tid & 63;
    float* gs = &sGeo[wave * 960];
#pragma unroll
    for (int q = 1; q < 16; ++q) gs[lane * 15 + (q - 1)] = outv[q];
    __syncthreads();
    const size_t wbase = (size_t)(blockIdx.x * 256 + wave * 64) * 15;
#pragma unroll
    for (int j = 0; j < 15; ++j)
        out_geo[wbase + (size_t)(j * 64 + lane)] = gs[j * 64 + lane];
}

extern "C" void kernel_launch(void* const* d_in, const int* in_sizes, int n_in,
                              void* d_out, int out_size, void* d_ws, size_t ws_size,
                              hipStream_t stream) {
    const float* xyzs   = (const float*)d_in[0];
    const float* tables = (const float*)d_in[1];
    const float* W1     = (const float*)d_in[2];
    const float* W2     = (const float*)d_in[3];
    float* out = (float*)d_out;

    const int N = in_sizes[0] / 3;

    // Replicate reference RES computation bit-for-bit in float64.
    ResParams rp;
    const double PLS = exp(log(2048.0 / 16.0) / 15.0);
    for (int l = 0; l < NLEV; ++l) {
        const double r = ceil(16.0 * pow(PLS, (double)l));
        rp.res[l] = (int)r;
        const long long s = (long long)r + 1;
        rp.dense[l] = (s * s * s <= (long long)TSIZE) ? 1 : 0;
    }
    // Static grouping assumes levels 0..4 dense, 5..15 hashed — verify.
    bool pattern_ok = true;
    for (int l = 0; l < NLEV; ++l)
        if (rp.dense[l] != (l < 5 ? 1 : 0)) pattern_ok = false;

    float* out_sigma = out;
    float* out_geo   = out + N;

    // ws layout: enc_ws (uint[16][N]) | tbl_bf (uint[16*TSIZE]) | W1t | W2c
    const size_t encB = (size_t)NLEV * (size_t)N * 4;         // 128 MB
    const size_t tblB = (size_t)NLEV * (size_t)TSIZE * 4;     // 32 MB
    const size_t w1B  = 2048 * 4, w2B = 1024 * 4;
    const size_t need = encB + tblB + w1B + w2B;

    if (pattern_ok && ws_size >= need) {
        unsigned* enc_ws = (unsigned*)d_ws;
        unsigned* tbl_bf = (unsigned*)((char*)d_ws + encB);
        float*    W1t    = (float*)((char*)d_ws + encB + tblB);
        float*    W2c    = (float*)((char*)d_ws + encB + tblB + w1B);

        prep_kernel<<<dim3((NLEV * TSIZE * 2) / 4 / 256), dim3(256), 0, stream>>>(
            tables, W1, W2, tbl_bf, W1t, W2c);

        const dim3 grid(N / 256), block(256);
        enc_dense_kernel<<<grid, block, 0, stream>>>(xyzs, tables, enc_ws, rp, N);
        for (int l = 5; l < NLEV; ++l)
            enc_hash_kernel<<<grid, block, 0, stream>>>(
                xyzs, tbl_bf, enc_ws, l, rp.res[l], N);

        mlp_kernel<<<dim3(N / 512), block, 0, stream>>>(
            enc_ws, W1t, W2c, out_sigma, out_geo, N);
    } else {
        hashgrid_fused_kernel<<<dim3(N / 256), dim3(256), 0, stream>>>(
            xyzs, tables, W1, W2, out_sigma, out_geo, rp);
    }
}

// Round 6
// 1233.148 us; speedup vs baseline: 1.5737x; 1.1590x over previous
//
#include <hip/hip_runtime.h>
#include <math.h>

#define NLEV 16
#define TSIZE 524288
#define TMASK (TSIZE - 1)
#define P1 2654435761u
#define P2 805459861u
#define NB 32768   // 15-bit Morton buckets (res-32 cubes)

struct Params {
    int res[NLEV];
    unsigned ncell[5];   // (res+1)^3 for dense levels
    unsigned doff[5];    // float4 offsets into dense_pairs
};

__device__ __forceinline__ float clamp01f(float v) {
    return fminf(fmaxf(v, 0.0f), 1.0f);
}
__device__ __forceinline__ unsigned f2bf(float f) {
    union { float f; unsigned u; } c; c.f = f;
    return (c.u + 0x7FFFu + ((c.u >> 16) & 1u)) >> 16;
}
__device__ __forceinline__ float bflo(unsigned u) {
    union { unsigned u; float f; } c; c.u = u << 16; return c.f;
}
__device__ __forceinline__ float bfhi(unsigned u) {
    union { unsigned u; float f; } c; c.u = u & 0xFFFF0000u; return c.f;
}
__device__ __forceinline__ unsigned spread5(unsigned v) {
    return (v & 1u) | ((v & 2u) << 2) | ((v & 4u) << 4) |
           ((v & 8u) << 6) | ((v & 16u) << 8);
}
__device__ __forceinline__ unsigned morton_key(float x0, float y0, float z0) {
    unsigned kx = min(31u, (unsigned)(x0 * 32.0f));
    unsigned ky = min(31u, (unsigned)(y0 * 32.0f));
    unsigned kz = min(31u, (unsigned)(z0 * 32.0f));
    return spread5(kx) | (spread5(ky) << 1) | (spread5(kz) << 2);
}

// ---------------- prep: build bf16 hash tables, fp32 dense pair-tables -----
__global__ __launch_bounds__(256) void prep_kernel(
    const float* __restrict__ tables,
    const float* __restrict__ W1,
    const float* __restrict__ W2,
    unsigned* __restrict__ tbl_bf,       // [11][TSIZE] packed bf16 (levels 5-15)
    float4* __restrict__ dense_pairs,    // overlapping pairs, fp32
    float* __restrict__ W1t, float* __restrict__ W2c,
    Params rp)
{
    const unsigned t = blockIdx.x * 256 + threadIdx.x;  // [0, 16*TSIZE)
    const unsigned l = t >> 19, c = t & TMASK;
    const float2* t2 = (const float2*)tables;
    if (l >= 5) {
        const float2 v = t2[(size_t)l * TSIZE + c];
        tbl_bf[(size_t)(l - 5) * TSIZE + c] = f2bf(v.x) | (f2bf(v.y) << 16);
    } else if (c < rp.ncell[l]) {
        const float2 a = t2[(size_t)l * TSIZE + c];
        const float2 b = t2[(size_t)l * TSIZE + c + 1];   // c+1 <= ncell < TSIZE
        dense_pairs[rp.doff[l] + c] = make_float4(a.x, a.y, b.x, b.y);
    }
    if (blockIdx.x == 0) {
        for (int i = threadIdx.x; i < 2048; i += 256)
            W1t[(i & 63) * 32 + (i >> 6)] = W1[i];
        for (int i = threadIdx.x; i < 1024; i += 256)
            W2c[i] = W2[i];
    }
}

// ---------------- counting sort by Morton key ------------------------------
__global__ __launch_bounds__(256) void zero_kernel(unsigned* __restrict__ hist) {
    hist[blockIdx.x * 256 + threadIdx.x] = 0u;
}

__global__ __launch_bounds__(256) void hist_kernel(
    const float* __restrict__ xyzs, unsigned* __restrict__ hist)
{
    const int gid = blockIdx.x * 256 + threadIdx.x;
    const float x0 = clamp01f((xyzs[3 * gid + 0] + 1.0f) * 0.5f);
    const float y0 = clamp01f((xyzs[3 * gid + 1] + 1.0f) * 0.5f);
    const float z0 = clamp01f((xyzs[3 * gid + 2] + 1.0f) * 0.5f);
    atomicAdd(&hist[morton_key(x0, y0, z0)], 1u);
}

__global__ __launch_bounds__(1024) void scan_kernel(
    const unsigned* __restrict__ hist, unsigned* __restrict__ work)
{
    __shared__ unsigned part[1024];
    const int tid = threadIdx.x;
    unsigned loc[32], s = 0;
#pragma unroll
    for (int i = 0; i < 32; ++i) { loc[i] = hist[tid * 32 + i]; s += loc[i]; }
    part[tid] = s; __syncthreads();
    for (int st = 1; st < 1024; st <<= 1) {
        unsigned t = (tid >= st) ? part[tid - st] : 0u;
        __syncthreads();
        part[tid] += t;
        __syncthreads();
    }
    unsigned base = (tid == 0) ? 0u : part[tid - 1];
#pragma unroll
    for (int i = 0; i < 32; ++i) { work[tid * 32 + i] = base; base += loc[i]; }
}

__global__ __launch_bounds__(256) void scatter_kernel(
    const float* __restrict__ xyzs, unsigned* __restrict__ work,
    float4* __restrict__ sorted, unsigned* __restrict__ perm)
{
    const int gid = blockIdx.x * 256 + threadIdx.x;
    const float x0 = clamp01f((xyzs[3 * gid + 0] + 1.0f) * 0.5f);
    const float y0 = clamp01f((xyzs[3 * gid + 1] + 1.0f) * 0.5f);
    const float z0 = clamp01f((xyzs[3 * gid + 2] + 1.0f) * 0.5f);
    const unsigned pos = atomicAdd(&work[morton_key(x0, y0, z0)], 1u);
    sorted[pos] = make_float4(x0, y0, z0, 0.0f);
    perm[pos] = (unsigned)gid;
}

// ---------------- dense levels 0..4 on sorted points (fp32 pair-gathers) ---
__global__ __launch_bounds__(256) void enc_dense_sorted(
    const float4* __restrict__ sorted,
    const float4* __restrict__ dense_pairs,
    unsigned* __restrict__ enc_ws,
    Params rp, int N)
{
    const int gid = blockIdx.x * 256 + threadIdx.x;
    const float4 p = sorted[gid];
    const float x0 = p.x, y0 = p.y, z0 = p.z;

#pragma unroll
    for (int l = 0; l < 5; ++l) {
        const int res = rp.res[l];
        const float rf = (float)res;
        const float px = x0 * rf, py = y0 * rf, pz = z0 * rf;
        const float fx = floorf(px), fy = floorf(py), fz = floorf(pz);
        const float rx = px - fx, ry = py - fy, rz = pz - fz;
        const unsigned ix = (unsigned)fx, iy = (unsigned)fy, iz = (unsigned)fz;

        const unsigned s = (unsigned)(res + 1);
        const unsigned ss = s * s;
        const unsigned a = ix + s * iy + ss * iz;
        const float4* dpt = dense_pairs + rp.doff[l];
        // q(j,k): .xy = corner (0,j,k), .zw = corner (1,j,k)
        const float4 q00 = dpt[a];
        const float4 q01 = dpt[a + ss];
        const float4 q10 = dpt[a + s];
        const float4 q11 = dpt[a + s + ss];

        const float wx0 = 1.0f - rx, wy0 = 1.0f - ry, wz0 = 1.0f - rz;
        // corner order c=0..7 identical to reference (_OFFS): x slowest
        float e0, e1;
        e0  = (wx0 * wy0) * wz0 * q00.x;  e1  = (wx0 * wy0) * wz0 * q00.y;
        e0 += (wx0 * wy0) * rz  * q01.x;  e1 += (wx0 * wy0) * rz  * q01.y;
        e0 += (wx0 * ry ) * wz0 * q10.x;  e1 += (wx0 * ry ) * wz0 * q10.y;
        e0 += (wx0 * ry ) * rz  * q11.x;  e1 += (wx0 * ry ) * rz  * q11.y;
        e0 += (rx  * wy0) * wz0 * q00.z;  e1 += (rx  * wy0) * wz0 * q00.w;
        e0 += (rx  * wy0) * rz  * q01.z;  e1 += (rx  * wy0) * rz  * q01.w;
        e0 += (rx  * ry ) * wz0 * q10.z;  e1 += (rx  * ry ) * wz0 * q10.w;
        e0 += (rx  * ry ) * rz  * q11.z;  e1 += (rx  * ry ) * rz  * q11.w;

        __builtin_nontemporal_store(f2bf(e0) | (f2bf(e1) << 16),
                                    enc_ws + (size_t)l * N + gid);
    }
}

// ---------------- one hashed level on sorted points, 2 pts/thread ----------
template<int LEVEL>
__global__ __launch_bounds__(256) void enc_hash_sorted(
    const float4* __restrict__ sorted,
    const unsigned* __restrict__ tbl_bf,
    unsigned* __restrict__ enc_ws,
    int res, int N)
{
    const int g0 = blockIdx.x * 512 + threadIdx.x;
    const unsigned* tl = tbl_bf + (size_t)(LEVEL - 5) * TSIZE;
    const float rf = (float)res;

    int gid[2] = { g0, g0 + 256 };
    unsigned v[2][8];
    float rx[2], ry[2], rz[2];

#pragma unroll
    for (int p = 0; p < 2; ++p) {
        const float4 pt = sorted[gid[p]];
        const float px = pt.x * rf, py = pt.y * rf, pz = pt.z * rf;
        const float fx = floorf(px), fy = floorf(py), fz = floorf(pz);
        rx[p] = px - fx; ry[p] = py - fy; rz[p] = pz - fz;
        const unsigned ix = (unsigned)fx, iy = (unsigned)fy, iz = (unsigned)fz;
        const unsigned ax0 = ix,        ax1 = ix + 1u;
        const unsigned by0 = iy * P1,   by1 = (iy + 1u) * P1;
        const unsigned cz0 = iz * P2,   cz1 = (iz + 1u) * P2;
        unsigned idx[8];
        idx[0] = (ax0 ^ by0 ^ cz0) & TMASK;
        idx[1] = (ax0 ^ by0 ^ cz1) & TMASK;
        idx[2] = (ax0 ^ by1 ^ cz0) & TMASK;
        idx[3] = (ax0 ^ by1 ^ cz1) & TMASK;
        idx[4] = (ax1 ^ by0 ^ cz0) & TMASK;
        idx[5] = (ax1 ^ by0 ^ cz1) & TMASK;
        idx[6] = (ax1 ^ by1 ^ cz0) & TMASK;
        idx[7] = (ax1 ^ by1 ^ cz1) & TMASK;
#pragma unroll
        for (int c = 0; c < 8; ++c) v[p][c] = tl[idx[c]];
    }

#pragma unroll
    for (int p = 0; p < 2; ++p) {
        const float wx0 = 1.0f - rx[p], wy0 = 1.0f - ry[p], wz0 = 1.0f - rz[p];
        float e0 = 0.0f, e1 = 0.0f;
#pragma unroll
        for (int c = 0; c < 8; ++c) {
            const float wx = (c & 4) ? rx[p] : wx0;
            const float wy = (c & 2) ? ry[p] : wy0;
            const float wz = (c & 1) ? rz[p] : wz0;
            const float w = (wx * wy) * wz;
            e0 += w * bflo(v[p][c]);
            e1 += w * bfhi(v[p][c]);
        }
        __builtin_nontemporal_store(f2bf(e0) | (f2bf(e1) << 16),
                                    enc_ws + (size_t)LEVEL * N + gid[p]);
    }
}

// ---------------- MLP (2 pts/thread, LDS broadcast weights, scatter out) ---
__global__ __launch_bounds__(256) void mlp_scatter_kernel(
    const unsigned* __restrict__ enc_ws,
    const unsigned* __restrict__ perm,
    const float* __restrict__ W1t,
    const float* __restrict__ W2c,
    float* __restrict__ out_sigma,
    float* __restrict__ out_geo,
    int N)
{
    __shared__ float sW1t[64 * 32];
    __shared__ float sW2[64 * 16];

    const int tid = threadIdx.x;
    for (int i = tid; i < 2048; i += 256) sW1t[i] = W1t[i];
    for (int i = tid; i < 1024; i += 256) sW2[i] = W2c[i];
    __syncthreads();

    const int pt0 = blockIdx.x * 512 + tid;
    const int pt1 = pt0 + 256;

    float ea[32], eb[32];
#pragma unroll
    for (int l = 0; l < NLEV; ++l) {
        const unsigned u0 = __builtin_nontemporal_load(enc_ws + (size_t)l * N + pt0);
        const unsigned u1 = __builtin_nontemporal_load(enc_ws + (size_t)l * N + pt1);
        ea[2 * l] = bflo(u0); ea[2 * l + 1] = bfhi(u0);
        eb[2 * l] = bflo(u1); eb[2 * l + 1] = bfhi(u1);
    }

    float oa[16], ob[16];
#pragma unroll
    for (int q = 0; q < 16; ++q) { oa[q] = 0.0f; ob[q] = 0.0f; }

    for (int j = 0; j < 64; ++j) {
        const float4* wr = (const float4*)&sW1t[j * 32];
        float h0 = 0.0f, h1 = 0.0f;
#pragma unroll
        for (int k = 0; k < 8; ++k) {
            const float4 w = wr[k];
            h0 += ea[4 * k + 0] * w.x; h1 += eb[4 * k + 0] * w.x;
            h0 += ea[4 * k + 1] * w.y; h1 += eb[4 * k + 1] * w.y;
            h0 += ea[4 * k + 2] * w.z; h1 += eb[4 * k + 2] * w.z;
            h0 += ea[4 * k + 3] * w.w; h1 += eb[4 * k + 3] * w.w;
        }
        h0 = fmaxf(h0, 0.0f); h1 = fmaxf(h1, 0.0f);
        const float4* w2 = (const float4*)&sW2[j * 16];
#pragma unroll
        for (int q = 0; q < 4; ++q) {
            const float4 w = w2[q];
            oa[4 * q + 0] += h0 * w.x; ob[4 * q + 0] += h1 * w.x;
            oa[4 * q + 1] += h0 * w.y; ob[4 * q + 1] += h1 * w.y;
            oa[4 * q + 2] += h0 * w.z; ob[4 * q + 2] += h1 * w.z;
            oa[4 * q + 3] += h0 * w.w; ob[4 * q + 3] += h1 * w.w;
        }
    }

    const unsigned o0 = perm[pt0];
    const unsigned o1 = perm[pt1];
    out_sigma[o0] = expf(oa[0]);
    out_sigma[o1] = expf(ob[0]);
#pragma unroll
    for (int q = 1; q < 16; ++q)
        out_geo[(size_t)o0 * 15 + (q - 1)] = oa[q];
#pragma unroll
    for (int q = 1; q < 16; ++q)
        out_geo[(size_t)o1 * 15 + (q - 1)] = ob[q];
}

// ---------------- fallback: proven fused kernel (R1, passed) ---------------
__global__ __launch_bounds__(256) void hashgrid_fused_kernel(
    const float* __restrict__ xyzs,
    const float* __restrict__ tables,
    const float* __restrict__ W1,
    const float* __restrict__ W2,
    float* __restrict__ out_sigma,
    float* __restrict__ out_geo,
    Params rp, int ndense)
{
    __shared__ float sW1t[64 * 32];
    __shared__ float sW2[64 * 16];
    __shared__ float sGeo[256 * 15];

    const int tid = threadIdx.x;
    for (int i = tid; i < 2048; i += 256) {
        int k = i >> 6, j = i & 63;
        sW1t[j * 32 + k] = W1[i];
    }
    for (int i = tid; i < 1024; i += 256) sW2[i] = W2[i];
    __syncthreads();

    const int gid = blockIdx.x * 256 + tid;
    const float x0 = clamp01f((xyzs[3 * gid + 0] + 1.0f) * 0.5f);
    const float y0 = clamp01f((xyzs[3 * gid + 1] + 1.0f) * 0.5f);
    const float z0 = clamp01f((xyzs[3 * gid + 2] + 1.0f) * 0.5f);

    float enc[32];
    const float2* tb = (const float2*)tables;

#pragma unroll
    for (int l = 0; l < NLEV; ++l) {
        const int res = rp.res[l];
        const float rf = (float)res;
        const float px = x0 * rf, py = y0 * rf, pz = z0 * rf;
        const float fx = floorf(px), fy = floorf(py), fz = floorf(pz);
        const float rx = px - fx, ry = py - fy, rz = pz - fz;
        const unsigned ix = (unsigned)fx, iy = (unsigned)fy, iz = (unsigned)fz;

        unsigned idx[8];
        if (l < ndense) {
            const unsigned s = (unsigned)(res + 1);
            const unsigned ss = s * s;
            const unsigned base = ix + s * (iy + s * iz);
            idx[0] = base;          idx[1] = base + ss;
            idx[2] = base + s;      idx[3] = base + s + ss;
            idx[4] = base + 1u;     idx[5] = base + 1u + ss;
            idx[6] = base + 1u + s; idx[7] = base + 1u + s + ss;
        } else {
            const unsigned ax0 = ix,        ax1 = ix + 1u;
            const unsigned by0 = iy * P1,   by1 = (iy + 1u) * P1;
            const unsigned cz0 = iz * P2,   cz1 = (iz + 1u) * P2;
            idx[0] = (ax0 ^ by0 ^ cz0) & TMASK;
            idx[1] = (ax0 ^ by0 ^ cz1) & TMASK;
            idx[2] = (ax0 ^ by1 ^ cz0) & TMASK;
            idx[3] = (ax0 ^ by1 ^ cz1) & TMASK;
            idx[4] = (ax1 ^ by0 ^ cz0) & TMASK;
            idx[5] = (ax1 ^ by0 ^ cz1) & TMASK;
            idx[6] = (ax1 ^ by1 ^ cz0) & TMASK;
            idx[7] = (ax1 ^ by1 ^ cz1) & TMASK;
        }

        const float2* tl = tb + (size_t)l * TSIZE;
        float2 v[8];
#pragma unroll
        for (int c = 0; c < 8; ++c) v[c] = tl[idx[c]];

        const float wx0 = 1.0f - rx, wy0 = 1.0f - ry, wz0 = 1.0f - rz;
        float e0 = 0.0f, e1 = 0.0f;
#pragma unroll
        for (int c = 0; c < 8; ++c) {
            const float wx = (c & 4) ? rx : wx0;
            const float wy = (c & 2) ? ry : wy0;
            const float wz = (c & 1) ? rz : wz0;
            const float w = (wx * wy) * wz;
            e0 += w * v[c].x;
            e1 += w * v[c].y;
        }
        enc[2 * l]     = e0;
        enc[2 * l + 1] = e1;
    }

    float outv[16];
#pragma unroll
    for (int q = 0; q < 16; ++q) outv[q] = 0.0f;

    for (int j = 0; j < 64; ++j) {
        const float4* wrow = (const float4*)&sW1t[j * 32];
        float hj = 0.0f;
#pragma unroll
        for (int kk = 0; kk < 8; ++kk) {
            const float4 wv = wrow[kk];
            hj += enc[4 * kk + 0] * wv.x;
            hj += enc[4 * kk + 1] * wv.y;
            hj += enc[4 * kk + 2] * wv.z;
            hj += enc[4 * kk + 3] * wv.w;
        }
        hj = fmaxf(hj, 0.0f);
        const float4* w2row = (const float4*)&sW2[j * 16];
#pragma unroll
        for (int qq = 0; qq < 4; ++qq) {
            const float4 w2v = w2row[qq];
            outv[4 * qq + 0] += hj * w2v.x;
            outv[4 * qq + 1] += hj * w2v.y;
            outv[4 * qq + 2] += hj * w2v.z;
            outv[4 * qq + 3] += hj * w2v.w;
        }
    }

    out_sigma[gid] = expf(outv[0]);

    const int wave = tid >> 6;
    const int lane = tid & 63;
    float* gs = &sGeo[wave * 960];
#pragma unroll
    for (int q = 1; q < 16; ++q) gs[lane * 15 + (q - 1)] = outv[q];
    __syncthreads();
    const size_t wbase = (size_t)(blockIdx.x * 256 + wave * 64) * 15;
#pragma unroll
    for (int j = 0; j < 15; ++j)
        out_geo[wbase + (size_t)(j * 64 + lane)] = gs[j * 64 + lane];
}

extern "C" void kernel_launch(void* const* d_in, const int* in_sizes, int n_in,
                              void* d_out, int out_size, void* d_ws, size_t ws_size,
                              hipStream_t stream) {
    const float* xyzs   = (const float*)d_in[0];
    const float* tables = (const float*)d_in[1];
    const float* W1     = (const float*)d_in[2];
    const float* W2     = (const float*)d_in[3];
    float* out = (float*)d_out;

    const int N = in_sizes[0] / 3;

    // Replicate reference RES computation bit-for-bit in float64.
    Params rp;
    int ndense = 0;
    const double PLS = exp(log(2048.0 / 16.0) / 15.0);
    bool pattern_ok = true;
    for (int l = 0; l < NLEV; ++l) {
        const double r = ceil(16.0 * pow(PLS, (double)l));
        rp.res[l] = (int)r;
        const long long s = (long long)r + 1;
        const bool dense = (s * s * s <= (long long)TSIZE);
        if (dense) ndense = l + 1;
        if (dense != (l < 5)) pattern_ok = false;
    }
    unsigned doff = 0;
    if (pattern_ok) {
        for (int l = 0; l < 5; ++l) {
            const unsigned s = (unsigned)rp.res[l] + 1;
            rp.ncell[l] = s * s * s;
            rp.doff[l] = doff;
            doff += rp.ncell[l];
        }
    }

    float* out_sigma = out;
    float* out_geo   = out + N;

    // ws layout (16B-aligned blocks first):
    //   dense_pairs  doff   float4        (~5.7 MB)
    //   sorted       N      float4        (32 MB)
    //   enc_ws       16*N   u32           (128 MB)
    //   tbl_bf       11*T   u32           (22 MB)
    //   perm         N      u32           (8 MB)
    //   hist, work   NB     u32 each      (0.25 MB)
    //   W1t 2048 f32, W2c 1024 f32
    const size_t dpB  = (size_t)doff * 16;
    const size_t srtB = (size_t)N * 16;
    const size_t encB = (size_t)NLEV * N * 4;
    const size_t tblB = (size_t)11 * TSIZE * 4;
    const size_t prmB = (size_t)N * 4;
    const size_t hstB = (size_t)NB * 4;
    const size_t need = dpB + srtB + encB + tblB + prmB + 2 * hstB + 3072 * 4;

    if (pattern_ok && ws_size >= need) {
        char* w = (char*)d_ws;
        float4*   dense_pairs = (float4*)w;              w += dpB;
        float4*   sorted      = (float4*)w;              w += srtB;
        unsigned* enc_ws      = (unsigned*)w;            w += encB;
        unsigned* tbl_bf      = (unsigned*)w;            w += tblB;
        unsigned* perm        = (unsigned*)w;            w += prmB;
        unsigned* hist        = (unsigned*)w;            w += hstB;
        unsigned* work        = (unsigned*)w;            w += hstB;
        float*    W1t         = (float*)w;               w += 2048 * 4;
        float*    W2c         = (float*)w;

        prep_kernel<<<dim3(NLEV * TSIZE / 256), dim3(256), 0, stream>>>(
            tables, W1, W2, tbl_bf, dense_pairs, W1t, W2c, rp);

        zero_kernel<<<dim3(NB / 256), dim3(256), 0, stream>>>(hist);
        hist_kernel<<<dim3(N / 256), dim3(256), 0, stream>>>(xyzs, hist);
        scan_kernel<<<dim3(1), dim3(1024), 0, stream>>>(hist, work);
        scatter_kernel<<<dim3(N / 256), dim3(256), 0, stream>>>(
            xyzs, work, sorted, perm);

        enc_dense_sorted<<<dim3(N / 256), dim3(256), 0, stream>>>(
            sorted, dense_pairs, enc_ws, rp, N);

        const dim3 g2(N / 512), blk(256);
        enc_hash_sorted< 5><<<g2, blk, 0, stream>>>(sorted, tbl_bf, enc_ws, rp.res[ 5], N);
        enc_hash_sorted< 6><<<g2, blk, 0, stream>>>(sorted, tbl_bf, enc_ws, rp.res[ 6], N);
        enc_hash_sorted< 7><<<g2, blk, 0, stream>>>(sorted, tbl_bf, enc_ws, rp.res[ 7], N);
        enc_hash_sorted< 8><<<g2, blk, 0, stream>>>(sorted, tbl_bf, enc_ws, rp.res[ 8], N);
        enc_hash_sorted< 9><<<g2, blk, 0, stream>>>(sorted, tbl_bf, enc_ws, rp.res[ 9], N);
        enc_hash_sorted<10><<<g2, blk, 0, stream>>>(sorted, tbl_bf, enc_ws, rp.res[10], N);
        enc_hash_sorted<11><<<g2, blk, 0, stream>>>(sorted, tbl_bf, enc_ws, rp.res[11], N);
        enc_hash_sorted<12><<<g2, blk, 0, stream>>>(sorted, tbl_bf, enc_ws, rp.res[12], N);
        enc_hash_sorted<13><<<g2, blk, 0, stream>>>(sorted, tbl_bf, enc_ws, rp.res[13], N);
        enc_hash_sorted<14><<<g2, blk, 0, stream>>>(sorted, tbl_bf, enc_ws, rp.res[14], N);
        enc_hash_sorted<15><<<g2, blk, 0, stream>>>(sorted, tbl_bf, enc_ws, rp.res[15], N);

        mlp_scatter_kernel<<<dim3(N / 512), blk, 0, stream>>>(
            enc_ws, perm, W1t, W2c, out_sigma, out_geo, N);
    } else {
        hashgrid_fused_kernel<<<dim3(N / 256), dim3(256), 0, stream>>>(
            xyzs, tables, W1, W2, out_sigma, out_geo, rp, ndense);
    }
}